// Round 6
// baseline (1916.390 us; speedup 1.0000x reference)
//
#include <hip/hip_runtime.h>
#include <hip/hip_cooperative_groups.h>

namespace cg = cooperative_groups;

#define EPS 1e-10f
#define HALF_LN2PI 0.91893853320467274f

// b=16, win=14, w=6, ww=36, B_T=32, K=3, Bkk=288 (=i), C_T=32, HH=16
// W flat: [i=288][c=32][hr=4][m=4]
// Pt per (bb,p): [i=288][hc=4][m=4] = patchflat[base(p)+m*4+hc], base(p)=(p/6)*96+(p%6)*16
// Grid: 2304 blocks = (blk = bb*36+p)*4 + iq, 128 threads (2 waves), wave owns 36 i.
// lane = cl*4+hr; thread covers c in {cl, cl+16}, 4 hc each.
// Mpart row per (bid,wave): [(bid*2+wave)*1152 + k*64+lane]; blk's 8 rows are contiguous.
// acc k: [0..3]=S1a [4..7]=S2a [8..11]=S1b [12..15]=S2b [16]=sRa [17]=sRb

template <int IT>
__device__ __forceinline__ void m_step(const float* __restrict__ WT,
    const float* __restrict__ Pt, const float* __restrict__ actl,
    const float* __restrict__ invd, const float* __restrict__ apc,
    const int wave, const int lane, float* __restrict__ out)
{
    float acc[18];
#pragma unroll
    for (int k = 0; k < 18; ++k) acc[k] = 0.f;

    float4 wva = *(const float4*)WT;
    float4 wvb = *(const float4*)(WT + 256);
    float ra = (IT == 0) ? 0.03125f : apc[0];
    float rb = (IT == 0) ? 0.03125f : apc[16];

#pragma unroll 4
    for (int t = 0; t < 36; ++t) {
        const int il = wave * 36 + t;
        const int tn = (t < 35) ? t + 1 : 35;
        const float4 nwa = *(const float4*)(WT + (size_t)tn * 512);
        const float4 nwb = *(const float4*)(WT + (size_t)tn * 512 + 256);
        float nra = 0.03125f, nrb = 0.03125f;
        if (IT > 0) { nra = apc[(size_t)tn * 32]; nrb = apc[(size_t)tn * 32 + 16]; }

        float Ra, Rb;
        if (IT == 0) { Ra = 0.03125f; Rb = 0.03125f; }
        else { const float inv = invd[il]; Ra = fmaf(ra, inv, EPS); Rb = fmaf(rb, inv, EPS); }
        const float a_in = actl[il];
        const float R4a = Ra * a_in, R4b = Rb * a_in;
        acc[16] += R4a; acc[17] += R4b;
#pragma unroll
        for (int hc = 0; hc < 4; ++hc) {
            const float4 pv = *(const float4*)&Pt[il * 16 + hc * 4];
            const float Va = wva.x * pv.x + wva.y * pv.y + wva.z * pv.z + wva.w * pv.w;
            const float Vb = wvb.x * pv.x + wvb.y * pv.y + wvb.z * pv.z + wvb.w * pv.w;
            acc[hc]      = fmaf(R4a, Va, acc[hc]);
            acc[4 + hc]  = fmaf(R4a * Va, Va, acc[4 + hc]);
            acc[8 + hc]  = fmaf(R4b, Vb, acc[8 + hc]);
            acc[12 + hc] = fmaf(R4b * Vb, Vb, acc[12 + hc]);
        }
        wva = nwa; wvb = nwb; ra = nra; rb = nrb;
    }
#pragma unroll
    for (int k = 0; k < 18; ++k) out[k * 64 + lane] = acc[k];
}

__device__ __forceinline__ void compute_stats(const float* __restrict__ mpb,
    const int lane, const float lam, const float bva, const float bvb,
    const float baa, const float bab,
    float* __restrict__ mu, float* __restrict__ n2, float* __restrict__ hl,
    float* __restrict__ a2)
{
    float s[18];
#pragma unroll
    for (int k = 0; k < 18; ++k) {
        float v = 0.f;
#pragma unroll
        for (int r = 0; r < 8; ++r) v += mpb[(size_t)r * 1152 + k * 64 + lane];
        s[k] = v;
    }
#pragma unroll
    for (int q = 0; q < 2; ++q) {
        const float sR = s[16 + q];
        float ls = 0.f;
#pragma unroll
        for (int hc = 0; hc < 4; ++hc) {
            const float S1 = s[q * 8 + hc], S2 = s[q * 8 + 4 + hc];
            const float m = S1 / sR;
            float ss = S2 / sR - m * m;
            ss = fmaxf(ss, 1e-30f);
            mu[q * 4 + hc] = m;
            n2[q * 4 + hc] = -0.5f / ss;
            hl[q * 4 + hc] = -0.5f * __logf(ss) - HALF_LN2PI;
            ls += __logf(sqrtf(ss) + EPS);
        }
        ls += __shfl_xor(ls, 1);
        ls += __shfl_xor(ls, 2);
        const float bv = q ? bvb : bva, ba = q ? bab : baa;
        const float cost = sR * (16.0f * bv + ls);
        a2[q] = 1.0f / (1.0f + __expf(-lam * (ba - cost)));
    }
}

__device__ __forceinline__ void e_step(const float* __restrict__ WT,
    const float* __restrict__ Pt, const float* __restrict__ mu,
    const float* __restrict__ n2, const float* __restrict__ hl,
    const float aca, const float acb,
    float* __restrict__ apw, float* __restrict__ dnx,
    const int wave, const int lane, const int hr)
{
    float4 wva = *(const float4*)WT;
    float4 wvb = *(const float4*)(WT + 256);
#pragma unroll 4
    for (int t = 0; t < 36; ++t) {
        const int il = wave * 36 + t;
        const int tn = (t < 35) ? t + 1 : 35;
        const float4 nwa = *(const float4*)(WT + (size_t)tn * 512);
        const float4 nwb = *(const float4*)(WT + (size_t)tn * 512 + 256);
        float pea = 0.f, peb = 0.f;
#pragma unroll
        for (int hc = 0; hc < 4; ++hc) {
            const float4 pv = *(const float4*)&Pt[il * 16 + hc * 4];
            const float Va = wva.x * pv.x + wva.y * pv.y + wva.z * pv.z + wva.w * pv.w;
            const float Vb = wvb.x * pv.x + wvb.y * pv.y + wvb.z * pv.z + wvb.w * pv.w;
            const float da = Va - mu[hc], db = Vb - mu[4 + hc];
            pea += __expf(fmaf(da * da, n2[hc], hl[hc]));
            peb += __expf(fmaf(db * db, n2[4 + hc], hl[4 + hc]));
        }
        pea += __shfl_xor(pea, 1); pea += __shfl_xor(pea, 2);
        peb += __shfl_xor(peb, 1); peb += __shfl_xor(peb, 2);
        const float apa = aca * pea, apb = acb * peb;
        if (hr == 0) { apw[(size_t)t * 32] = apa; apw[(size_t)t * 32 + 16] = apb; }
        float dsum = apa + apb;
        dsum += __shfl_xor(dsum, 4);
        dsum += __shfl_xor(dsum, 8);
        dsum += __shfl_xor(dsum, 16);
        dsum += __shfl_xor(dsum, 32);
        if (lane == 0) atomicAdd(&dnx[t], dsum);
        wva = nwa; wvb = nwb;
    }
}

__global__ __launch_bounds__(128, 5)
void em_fused(const float* __restrict__ poses, const float* __restrict__ acts,
              const float* __restrict__ W, const float* __restrict__ beta_v,
              const float* __restrict__ beta_a, const float* __restrict__ lambda_p,
              float* __restrict__ ap_buf, float* __restrict__ Mpart,
              float* __restrict__ denom0, float* __restrict__ denom1,
              float* __restrict__ d_out)
{
    cg::grid_group grid = cg::this_grid();

    __shared__ __align__(16) float Pt_lds[1152];
    __shared__ float act_lds[72];
    __shared__ float invd_lds[72];

    const int tid  = threadIdx.x;
    const int wave = tid >> 6, lane = tid & 63;
    const int cl   = lane >> 2, hr = lane & 3;
    const int bid  = blockIdx.x;
    const int blk  = bid >> 2, iq = bid & 3;
    const int bb   = blk / 36, p = blk - bb * 36;
    const int i0   = iq * 72;
    const size_t apbase = (size_t)blk * 9216;

    // ---- gather patches ONCE; LDS-resident for all 5 passes ----
    {
        const int base = (p / 6) * 96 + (p % 6) * 16;
        for (int e = tid; e < 1152; e += 128) {
            int il = e >> 4, j = e & 15;
            int i = i0 + il;
            int hc = j >> 2, m = j & 3;
            int f = base + m * 4 + hc;              // flat (h,s)
            int h = f / 36, sp = f - h * 36;
            int y = sp / 6, x = sp - y * 6;
            int B = i / 9, kk = i - B * 9;
            int ki = kk / 3, kj = kk - ki * 3;
            Pt_lds[e] = poses[(size_t)((bb * 512 + h * 32 + B) * 14 + 2 * x + ki) * 14 + 2 * y + kj];
        }
        const int y = p / 6, x = p - y * 6;
        for (int e = tid; e < 72; e += 128) {
            int i = i0 + e;
            int B = i / 9, kk = i - B * 9;
            int ki = kk / 3, kj = kk - ki * 3;
            act_lds[e] = acts[(size_t)((bb * 32 + B) * 14 + 2 * x + ki) * 14 + 2 * y + kj];
        }
    }
    __syncthreads();

    const float* WT  = W + (size_t)(i0 + wave * 36) * 512 + (lane << 2);
    float* mpw       = Mpart + ((size_t)bid * 2 + wave) * 1152;
    const float* mpb = Mpart + (size_t)blk * 9216;
    const float* apc = ap_buf + apbase + (size_t)(i0 + wave * 36) * 32 + cl;
    float* apw       = ap_buf + apbase + (size_t)(i0 + wave * 36) * 32 + cl;
    const float lam = lambda_p[0];
    const float bva = beta_v[cl], bvb = beta_v[cl + 16];
    const float baa = beta_a[cl], bab = beta_a[cl + 16];

    // ---------------- iter 0: M ----------------
    m_step<0>(WT, Pt_lds, act_lds, invd_lds, apc, wave, lane, mpw);
    grid.sync();

    // ---------------- iter 0: stats + E -> denom0 ----------------
    {
        float mu[8], n2[8], hl[8], a2[2];
        compute_stats(mpb, lane, lam, bva, bvb, baa, bab, mu, n2, hl, a2);
        e_step(WT, Pt_lds, mu, n2, hl, a2[0], a2[1], apw,
               denom0 + bb * 288 + i0 + wave * 36, wave, lane, hr);
    }
    grid.sync();

    // ---------------- iter 1: M ----------------
    for (int e = tid; e < 72; e += 128)
        invd_lds[e] = 1.0f / (denom0[bb * 288 + i0 + e] + EPS);
    __syncthreads();
    m_step<1>(WT, Pt_lds, act_lds, invd_lds, apc, wave, lane, mpw);
    grid.sync();

    // ---------------- iter 1: stats + E -> denom1 ----------------
    {
        float mu[8], n2[8], hl[8], a2[2];
        compute_stats(mpb, lane, lam, bva, bvb, baa, bab, mu, n2, hl, a2);
        e_step(WT, Pt_lds, mu, n2, hl, a2[0], a2[1], apw,
               denom1 + bb * 288 + i0 + wave * 36, wave, lane, hr);
    }
    grid.sync();

    // ---------------- iter 2: M ----------------
    for (int e = tid; e < 72; e += 128)
        invd_lds[e] = 1.0f / (denom1[bb * 288 + i0 + e] + EPS);
    __syncthreads();
    m_step<1>(WT, Pt_lds, act_lds, invd_lds, apc, wave, lane, mpw);
    grid.sync();

    // ---------------- iter 2: stats -> output (iq==0 blocks) ----------------
    if (iq == 0) {
        float mu[8], n2[8], hl[8], a2[2];
        compute_stats(mpb, lane, lam, bva, bvb, baa, bab, mu, n2, hl, a2);
#pragma unroll
        for (int q = 0; q < 2; ++q) {
            const int c = cl + q * 16;
#pragma unroll
            for (int hc = 0; hc < 4; ++hc)
                d_out[(size_t)bb * 18432 + (size_t)(c * 36 + p) * 16 + hr * 4 + hc] = mu[q * 4 + hc];
            if (hr == 0)
                d_out[294912 + (size_t)bb * 1152 + c * 36 + p] = a2[q];
        }
    }
}

// ======================= fallback path (round-5 verified kernels) =======================

template <int IT>
__global__ __launch_bounds__(128)
void m_pass(const float* __restrict__ poses, const float* __restrict__ acts,
            float* __restrict__ Ptg, float* __restrict__ actp,
            const float* __restrict__ W,
            const float* __restrict__ ap_buf, const float* __restrict__ denom_prev,
            float* __restrict__ Mpart)
{
    __shared__ __align__(16) float Pt_lds[1152];
    __shared__ float act_lds[72];
    __shared__ float invd_lds[72];
    __shared__ __align__(16) float red[1152];

    const int tid  = threadIdx.x;
    const int wave = tid >> 6, lane = tid & 63;
    const int cl   = lane >> 2;
    const int bid  = blockIdx.x;
    const int blk  = bid >> 2, iq = bid & 3;
    const int bb   = blk / 36, p = blk - bb * 36;
    const int i0   = iq * 72;
    const size_t pbase  = (size_t)blk * 4608;
    const size_t apbase = (size_t)blk * 9216;

    if (IT == 0) {
        const int base = (p / 6) * 96 + (p % 6) * 16;
        for (int e = tid; e < 1152; e += 128) {
            int il = e >> 4, j = e & 15;
            int i = i0 + il;
            int hc = j >> 2, m = j & 3;
            int f = base + m * 4 + hc;
            int h = f / 36, sp = f - h * 36;
            int y = sp / 6, x = sp - y * 6;
            int B = i / 9, kk = i - B * 9;
            int ki = kk / 3, kj = kk - ki * 3;
            float v = poses[(size_t)((bb * 512 + h * 32 + B) * 14 + 2 * x + ki) * 14 + 2 * y + kj];
            Pt_lds[e] = v;
            Ptg[pbase + (size_t)i0 * 16 + e] = v;
        }
        const int y = p / 6, x = p - y * 6;
        for (int e = tid; e < 72; e += 128) {
            int i = i0 + e;
            int B = i / 9, kk = i - B * 9;
            int ki = kk / 3, kj = kk - ki * 3;
            float v = acts[(size_t)((bb * 32 + B) * 14 + 2 * x + ki) * 14 + 2 * y + kj];
            act_lds[e] = v;
            actp[blk * 288 + i] = v;
        }
    } else {
        const float4* src = (const float4*)(Ptg + pbase + (size_t)i0 * 16);
        float4* dst = (float4*)Pt_lds;
        for (int e = tid; e < 288; e += 128) dst[e] = src[e];
        for (int e = tid; e < 72; e += 128) {
            act_lds[e]  = actp[blk * 288 + i0 + e];
            invd_lds[e] = 1.0f / (denom_prev[bb * 288 + i0 + e] + EPS);
        }
    }
    __syncthreads();

    float acc[18];
#pragma unroll
    for (int k = 0; k < 18; ++k) acc[k] = 0.f;

    const float* Wt = W + (size_t)(i0 + wave * 36) * 512 + (lane << 2);
#pragma unroll 6
    for (int t = 0; t < 36; ++t) {
        const int il = wave * 36 + t;
        const float4 wva = *(const float4*)(Wt + (size_t)t * 512);
        const float4 wvb = *(const float4*)(Wt + (size_t)t * 512 + 256);
        float Ra, Rb;
        if (IT == 0) {
            Ra = 1.0f / 32.0f; Rb = 1.0f / 32.0f;
        } else {
            const int i = i0 + il;
            const float inv = invd_lds[il];
            Ra = fmaf(ap_buf[apbase + (size_t)i * 32 + cl],      inv, EPS);
            Rb = fmaf(ap_buf[apbase + (size_t)i * 32 + cl + 16], inv, EPS);
        }
        const float a_in = act_lds[il];
        const float R4a = Ra * a_in, R4b = Rb * a_in;
        acc[16] += R4a; acc[17] += R4b;
#pragma unroll
        for (int hc = 0; hc < 4; ++hc) {
            const float4 pv = *(const float4*)&Pt_lds[il * 16 + hc * 4];
            float Va = wva.x * pv.x + wva.y * pv.y + wva.z * pv.z + wva.w * pv.w;
            float Vb = wvb.x * pv.x + wvb.y * pv.y + wvb.z * pv.z + wvb.w * pv.w;
            acc[hc]      = fmaf(R4a, Va, acc[hc]);
            acc[4 + hc]  = fmaf(R4a * Va, Va, acc[4 + hc]);
            acc[8 + hc]  = fmaf(R4b, Vb, acc[8 + hc]);
            acc[12 + hc] = fmaf(R4b * Vb, Vb, acc[12 + hc]);
        }
    }

    if (wave == 1) {
#pragma unroll
        for (int k = 0; k < 18; ++k) red[lane * 18 + k] = acc[k];
    }
    __syncthreads();
    if (wave == 0) {
        float* mp = Mpart + (size_t)bid * 1152;
#pragma unroll
        for (int k = 0; k < 18; ++k)
            mp[k * 64 + lane] = acc[k] + red[lane * 18 + k];
    }
}

template <int FINAL>
__global__ __launch_bounds__(64)
void f_pass(float* __restrict__ Mpart, const float* __restrict__ beta_v,
            const float* __restrict__ beta_a, const float* __restrict__ lambda_p,
            float* __restrict__ d_out)
{
    const int lane = threadIdx.x;
    const int cl = lane >> 2, hr = lane & 3;
    const int blk = blockIdx.x;
    const int bb = blk / 36, p = blk - bb * 36;
    float* mp = Mpart + (size_t)blk * 4608;

    float s[18];
#pragma unroll
    for (int k = 0; k < 18; ++k)
        s[k] = mp[k * 64 + lane] + mp[1152 + k * 64 + lane]
             + mp[2304 + k * 64 + lane] + mp[3456 + k * 64 + lane];

    const float lam = lambda_p[0];
    float muv[8], n2v[8], hlv[8], av[2];
#pragma unroll
    for (int q = 0; q < 2; ++q) {
        const int c = cl + q * 16;
        const float sR = s[16 + q];
        float ls = 0.f;
#pragma unroll
        for (int hc = 0; hc < 4; ++hc) {
            const float S1 = s[q * 8 + hc];
            const float S2 = s[q * 8 + 4 + hc];
            const float mu = S1 / sR;
            float ss = S2 / sR - mu * mu;
            ss = fmaxf(ss, 1e-30f);
            muv[q * 4 + hc] = mu;
            n2v[q * 4 + hc] = -0.5f / ss;
            hlv[q * 4 + hc] = -0.5f * __logf(ss) - HALF_LN2PI;
            ls += __logf(sqrtf(ss) + EPS);
        }
        ls += __shfl_xor(ls, 1);
        ls += __shfl_xor(ls, 2);
        const float cost = sR * (16.0f * beta_v[c] + ls);
        av[q] = 1.0f / (1.0f + __expf(-lam * (beta_a[c] - cost)));
    }

    if (FINAL) {
#pragma unroll
        for (int q = 0; q < 2; ++q) {
            const int c = cl + q * 16;
#pragma unroll
            for (int hc = 0; hc < 4; ++hc)
                d_out[(size_t)bb * 18432 + (size_t)(c * 36 + p) * 16 + hr * 4 + hc] = muv[q * 4 + hc];
            if (hr == 0)
                d_out[294912 + (size_t)bb * 1152 + c * 36 + p] = av[q];
        }
    } else {
        asm volatile("s_waitcnt vmcnt(0)" ::: "memory");
#pragma unroll
        for (int q = 0; q < 2; ++q) {
#pragma unroll
            for (int hc = 0; hc < 4; ++hc) {
                const int ix = lane * 4 + q * 256 + hc;
                mp[ix]        = muv[q * 4 + hc];
                mp[512 + ix]  = n2v[q * 4 + hc];
                mp[1024 + ix] = hlv[q * 4 + hc];
            }
            if (hr == 0) mp[1536 + cl + q * 16] = av[q];
        }
    }
}

__global__ __launch_bounds__(128)
void e_pass(const float* __restrict__ Ptg, const float* __restrict__ Mpart,
            const float* __restrict__ W,
            float* __restrict__ ap_buf, float* __restrict__ denom_next)
{
    __shared__ __align__(16) float Pt_lds[1152];

    const int tid  = threadIdx.x;
    const int wave = tid >> 6, lane = tid & 63;
    const int cl   = lane >> 2, hr = lane & 3;
    const int bid  = blockIdx.x;
    const int blk  = bid >> 2, iq = bid & 3;
    const int bb   = blk / 36;
    const int i0   = iq * 72;
    const size_t pbase  = (size_t)blk * 4608;
    const size_t apbase = (size_t)blk * 9216;

    {
        const float4* src = (const float4*)(Ptg + pbase + (size_t)i0 * 16);
        float4* dst = (float4*)Pt_lds;
        for (int e = tid; e < 288; e += 128) dst[e] = src[e];
    }

    const float* st = Mpart + (size_t)blk * 4608;
    __align__(16) float mua[4], mub[4], na[4], nb[4], ha[4], hb[4];
    *(float4*)mua = *(const float4*)&st[lane * 4];
    *(float4*)mub = *(const float4*)&st[lane * 4 + 256];
    *(float4*)na  = *(const float4*)&st[512 + lane * 4];
    *(float4*)nb  = *(const float4*)&st[512 + lane * 4 + 256];
    *(float4*)ha  = *(const float4*)&st[1024 + lane * 4];
    *(float4*)hb  = *(const float4*)&st[1024 + lane * 4 + 256];
    const float aca = st[1536 + cl], acb = st[1536 + cl + 16];
    __syncthreads();

    const float* Wt = W + (size_t)(i0 + wave * 36) * 512 + (lane << 2);
#pragma unroll 6
    for (int t = 0; t < 36; ++t) {
        const int il = wave * 36 + t;
        const int i = i0 + il;
        const float4 wva = *(const float4*)(Wt + (size_t)t * 512);
        const float4 wvb = *(const float4*)(Wt + (size_t)t * 512 + 256);
        float pea = 0.f, peb = 0.f;
#pragma unroll
        for (int hc = 0; hc < 4; ++hc) {
            const float4 pv = *(const float4*)&Pt_lds[il * 16 + hc * 4];
            float Va = wva.x * pv.x + wva.y * pv.y + wva.z * pv.z + wva.w * pv.w;
            float Vb = wvb.x * pv.x + wvb.y * pv.y + wvb.z * pv.z + wvb.w * pv.w;
            float da = Va - mua[hc];
            float db = Vb - mub[hc];
            pea += __expf(fmaf(da * da, na[hc], ha[hc]));
            peb += __expf(fmaf(db * db, nb[hc], hb[hc]));
        }
        pea += __shfl_xor(pea, 1);
        pea += __shfl_xor(pea, 2);
        peb += __shfl_xor(peb, 1);
        peb += __shfl_xor(peb, 2);
        const float apa = aca * pea;
        const float apb = acb * peb;
        if (hr == 0) {
            ap_buf[apbase + (size_t)i * 32 + cl]      = apa;
            ap_buf[apbase + (size_t)i * 32 + cl + 16] = apb;
        }
        float dsum = apa + apb;
        dsum += __shfl_xor(dsum, 4);
        dsum += __shfl_xor(dsum, 8);
        dsum += __shfl_xor(dsum, 16);
        dsum += __shfl_xor(dsum, 32);
        if (lane == 0)
            atomicAdd(&denom_next[bb * 288 + i], dsum);
    }
}

extern "C" void kernel_launch(void* const* d_in, const int* in_sizes, int n_in,
                              void* d_out, int out_size, void* d_ws, size_t ws_size,
                              hipStream_t stream)
{
    const float* lambda_p = (const float*)d_in[0];
    const float* poses    = (const float*)d_in[1];
    const float* acts     = (const float*)d_in[2];
    const float* W        = (const float*)d_in[3];
    const float* beta_v   = (const float*)d_in[4];
    const float* beta_a   = (const float*)d_in[5];
    float* out = (float*)d_out;

    // Workspace union (10,791,936 floats = 43.2 MB, identical to verified round-5):
    //   ap_buf  : 5,308,416
    //   X region: 5,474,304
    //     fused   : MpartF = X (2304*2*1152 = 5,308,416)
    //     fallback: Ptg = X (2,654,208); actp = X+2,654,208 (165,888); Mpart = X+2,820,096 (2,654,208)
    //   denom0/denom1: 4608 each
    float* ws     = (float*)d_ws;
    float* ap_buf = ws;
    float* xreg   = ws + 5308416;
    float* denom0 = ws + 5308416 + 5474304;
    float* denom1 = denom0 + 4608;

    hipMemsetAsync(denom0, 0, 2 * 4608 * sizeof(float), stream);

    void* args[] = {
        (void*)&poses, (void*)&acts, (void*)&W, (void*)&beta_v, (void*)&beta_a,
        (void*)&lambda_p, (void*)&ap_buf, (void*)&xreg, (void*)&denom0,
        (void*)&denom1, (void*)&out
    };
    hipError_t err = hipLaunchCooperativeKernel((void*)em_fused, dim3(2304), dim3(128),
                                                args, 0, stream);
    if (err != hipSuccess) {
        // fallback: verified round-5 multi-kernel path
        float* Ptg   = xreg;
        float* actp  = xreg + 2654208;
        float* Mpart = xreg + 2820096;
        m_pass<0><<<2304, 128, 0, stream>>>(poses, acts, Ptg, actp, W, ap_buf, denom1, Mpart);
        f_pass<0><<<576, 64, 0, stream>>>(Mpart, beta_v, beta_a, lambda_p, out);
        e_pass<<<2304, 128, 0, stream>>>(Ptg, Mpart, W, ap_buf, denom0);
        m_pass<1><<<2304, 128, 0, stream>>>(poses, acts, Ptg, actp, W, ap_buf, denom0, Mpart);
        f_pass<0><<<576, 64, 0, stream>>>(Mpart, beta_v, beta_a, lambda_p, out);
        e_pass<<<2304, 128, 0, stream>>>(Ptg, Mpart, W, ap_buf, denom1);
        m_pass<2><<<2304, 128, 0, stream>>>(poses, acts, Ptg, actp, W, ap_buf, denom1, Mpart);
        f_pass<1><<<576, 64, 0, stream>>>(Mpart, beta_v, beta_a, lambda_p, out);
    }
}

// Round 7
// 1758.870 us; speedup vs baseline: 1.0896x; 1.0896x over previous
//
#include <hip/hip_runtime.h>

#define EPS 1e-10f
#define HALF_LN2PI 0.91893853320467274f
#define LOG2E 1.4426950408889634f

// b=16, win=14, w=6, ww=36, B_T=32, K=3, Bkk=288 (=i), C_T=32, HH=16
// W flat: [i=288][c=32][hr=4][m=4]
// Pt per (bb,p): [i=288][hc=4][m=4] = patchflat[base(p)+m*4+hc], base(p)=(p/6)*96+(p%6)*16
//
// Grid (m/e): 2304 blocks = (blk = bb*36+p)*4 + iq, 128 threads (2 waves).
// Wave handles 36 i: i = iq*72 + wave*36 + t. 9 blocks/CU, 18 waves/CU (all resident).
// lane = cl*4+hr; thread covers c in {cl, cl+16}, 4 hc each.
// Mpart[bid][k*64+lane], k: [0..3]=S1a [4..7]=S2a [8..11]=S1b [12..15]=S2b [16]=sRa [17]=sRb
// f_pass reduces Mpart over the 4 iq partials and writes stats IN PLACE at
// Mpart[blk*4608 + {0:mu, 512:n2*log2e, 1024:hl*log2e, 1536:a}].
// NOTE (round 6 post-mortem): grid.sync() cooperative fusion = device-scope L2
// flush per sync -> 770 MB HBM traffic, 6% VALU. Dispatch boundaries are the
// cheap coherence mechanism on MI355X; keep the multi-kernel structure.

__device__ __forceinline__ float fexp2(float x) {
    float r;
    asm("v_exp_f32 %0, %1" : "=v"(r) : "v"(x));
    return r;
}

template <int IT>
__global__ __launch_bounds__(128, 5)
void m_pass(const float* __restrict__ poses, const float* __restrict__ acts,
            float* __restrict__ Ptg, float* __restrict__ actp,
            const float* __restrict__ W,
            const float* __restrict__ ap_buf, const float* __restrict__ denom_prev,
            float* __restrict__ Mpart)
{
    __shared__ __align__(16) float Pt_lds[1152];   // 72 i x 16
    __shared__ float act_lds[72];
    __shared__ float invd_lds[72];
    __shared__ __align__(16) float red[1152];

    const int tid  = threadIdx.x;
    const int wave = tid >> 6, lane = tid & 63;
    const int cl   = lane >> 2;
    const int bid  = blockIdx.x;
    const int blk  = bid >> 2, iq = bid & 3;
    const int bb   = blk / 36, p = blk - bb * 36;
    const int i0   = iq * 72;
    const size_t pbase  = (size_t)blk * 4608;
    const size_t apbase = (size_t)blk * 9216;

    if (IT == 0) {
        const int base = (p / 6) * 96 + (p % 6) * 16;
        for (int e = tid; e < 1152; e += 128) {
            int il = e >> 4, j = e & 15;
            int i = i0 + il;
            int hc = j >> 2, m = j & 3;
            int f = base + m * 4 + hc;              // flat (h,s)
            int h = f / 36, sp = f - h * 36;
            int y = sp / 6, x = sp - y * 6;
            int B = i / 9, kk = i - B * 9;
            int ki = kk / 3, kj = kk - ki * 3;
            float v = poses[(size_t)((bb * 512 + h * 32 + B) * 14 + 2 * x + ki) * 14 + 2 * y + kj];
            Pt_lds[e] = v;
            Ptg[pbase + (size_t)i0 * 16 + e] = v;
        }
        const int y = p / 6, x = p - y * 6;
        for (int e = tid; e < 72; e += 128) {
            int i = i0 + e;
            int B = i / 9, kk = i - B * 9;
            int ki = kk / 3, kj = kk - ki * 3;
            float v = acts[(size_t)((bb * 32 + B) * 14 + 2 * x + ki) * 14 + 2 * y + kj];
            act_lds[e] = v;
            actp[blk * 288 + i] = v;
        }
    } else {
        const float4* src = (const float4*)(Ptg + pbase + (size_t)i0 * 16);
        float4* dst = (float4*)Pt_lds;
        for (int e = tid; e < 288; e += 128) dst[e] = src[e];
        for (int e = tid; e < 72; e += 128) {
            act_lds[e]  = actp[blk * 288 + i0 + e];
            invd_lds[e] = 1.0f / (denom_prev[bb * 288 + i0 + e] + EPS);
        }
    }
    __syncthreads();

    float acc[18];
#pragma unroll
    for (int k = 0; k < 18; ++k) acc[k] = 0.f;

    const float* Wt  = W + (size_t)(i0 + wave * 36) * 512 + (lane << 2);
    const float* apc = ap_buf + apbase + (size_t)(i0 + wave * 36) * 32 + cl;

#pragma unroll
    for (int t = 0; t < 36; ++t) {
        const int il = wave * 36 + t;
        const float4 wva = *(const float4*)(Wt + (size_t)t * 512);
        const float4 wvb = *(const float4*)(Wt + (size_t)t * 512 + 256);
        float Ra, Rb;
        if (IT == 0) {
            Ra = 1.0f / 32.0f; Rb = 1.0f / 32.0f;
        } else {
            const float inv = invd_lds[il];
            Ra = fmaf(apc[(size_t)t * 32],      inv, EPS);
            Rb = fmaf(apc[(size_t)t * 32 + 16], inv, EPS);
        }
        const float a_in = act_lds[il];
        const float R4a = Ra * a_in, R4b = Rb * a_in;
        acc[16] += R4a; acc[17] += R4b;
#pragma unroll
        for (int hc = 0; hc < 4; ++hc) {
            const float4 pv = *(const float4*)&Pt_lds[il * 16 + hc * 4];
            float Va = wva.x * pv.x + wva.y * pv.y + wva.z * pv.z + wva.w * pv.w;
            float Vb = wvb.x * pv.x + wvb.y * pv.y + wvb.z * pv.z + wvb.w * pv.w;
            acc[hc]      = fmaf(R4a, Va, acc[hc]);
            acc[4 + hc]  = fmaf(R4a * Va, Va, acc[4 + hc]);
            acc[8 + hc]  = fmaf(R4b, Vb, acc[8 + hc]);
            acc[12 + hc] = fmaf(R4b * Vb, Vb, acc[12 + hc]);
        }
    }

    if (wave == 1) {
#pragma unroll
        for (int k = 0; k < 18; ++k) red[lane * 18 + k] = acc[k];
    }
    __syncthreads();
    if (wave == 0) {
        float* mp = Mpart + (size_t)bid * 1152;
#pragma unroll
        for (int k = 0; k < 18; ++k)
            mp[k * 64 + lane] = acc[k] + red[lane * 18 + k];
    }
}

template <int FINAL>
__global__ __launch_bounds__(64)
void f_pass(float* __restrict__ Mpart, const float* __restrict__ beta_v,
            const float* __restrict__ beta_a, const float* __restrict__ lambda_p,
            float* __restrict__ d_out)
{
    const int lane = threadIdx.x;
    const int cl = lane >> 2, hr = lane & 3;
    const int blk = blockIdx.x;
    const int bb = blk / 36, p = blk - bb * 36;
    float* mp = Mpart + (size_t)blk * 4608;

    float s[18];
#pragma unroll
    for (int k = 0; k < 18; ++k)
        s[k] = mp[k * 64 + lane] + mp[1152 + k * 64 + lane]
             + mp[2304 + k * 64 + lane] + mp[3456 + k * 64 + lane];

    const float lam = lambda_p[0];
    float muv[8], n2v[8], hlv[8], av[2];
#pragma unroll
    for (int q = 0; q < 2; ++q) {
        const int c = cl + q * 16;
        const float sR = s[16 + q];
        float ls = 0.f;
#pragma unroll
        for (int hc = 0; hc < 4; ++hc) {
            const float S1 = s[q * 8 + hc];
            const float S2 = s[q * 8 + 4 + hc];
            const float mu = S1 / sR;
            float ss = S2 / sR - mu * mu;
            ss = fmaxf(ss, 1e-30f);
            muv[q * 4 + hc] = mu;
            // pre-scaled by log2e so e_pass uses a single v_exp_f32 (2^x)
            n2v[q * 4 + hc] = (-0.5f / ss) * LOG2E;
            hlv[q * 4 + hc] = (-0.5f * __logf(ss) - HALF_LN2PI) * LOG2E;
            ls += __logf(sqrtf(ss) + EPS);
        }
        ls += __shfl_xor(ls, 1);
        ls += __shfl_xor(ls, 2);
        const float cost = sR * (16.0f * beta_v[c] + ls);
        av[q] = 1.0f / (1.0f + __expf(-lam * (beta_a[c] - cost)));
    }

    if (FINAL) {
#pragma unroll
        for (int q = 0; q < 2; ++q) {
            const int c = cl + q * 16;
#pragma unroll
            for (int hc = 0; hc < 4; ++hc)
                d_out[(size_t)bb * 18432 + (size_t)(c * 36 + p) * 16 + hr * 4 + hc] = muv[q * 4 + hc];
            if (hr == 0)
                d_out[294912 + (size_t)bb * 1152 + c * 36 + p] = av[q];
        }
    } else {
        // stats written IN PLACE over Mpart[blk]; fence so no store passes an
        // in-flight sibling-lane load of the same region.
        asm volatile("s_waitcnt vmcnt(0)" ::: "memory");
#pragma unroll
        for (int q = 0; q < 2; ++q) {
#pragma unroll
            for (int hc = 0; hc < 4; ++hc) {
                const int ix = lane * 4 + q * 256 + hc;
                mp[ix]        = muv[q * 4 + hc];
                mp[512 + ix]  = n2v[q * 4 + hc];
                mp[1024 + ix] = hlv[q * 4 + hc];
            }
            if (hr == 0) mp[1536 + cl + q * 16] = av[q];
        }
    }
}

__global__ __launch_bounds__(128, 5)
void e_pass(const float* __restrict__ Ptg, const float* __restrict__ Mpart,
            const float* __restrict__ W,
            float* __restrict__ ap_buf, float* __restrict__ denom_next)
{
    __shared__ __align__(16) float Pt_lds[1152];

    const int tid  = threadIdx.x;
    const int wave = tid >> 6, lane = tid & 63;
    const int cl   = lane >> 2, hr = lane & 3;
    const int bid  = blockIdx.x;
    const int blk  = bid >> 2, iq = bid & 3;
    const int bb   = blk / 36;
    const int i0   = iq * 72;
    const size_t pbase  = (size_t)blk * 4608;
    const size_t apbase = (size_t)blk * 9216;

    {
        const float4* src = (const float4*)(Ptg + pbase + (size_t)i0 * 16);
        float4* dst = (float4*)Pt_lds;
        for (int e = tid; e < 288; e += 128) dst[e] = src[e];
    }

    // stats straight to registers (written by f_pass into Mpart[blk])
    const float* st = Mpart + (size_t)blk * 4608;
    __align__(16) float mua[4], mub[4], na[4], nb[4], ha[4], hb[4];
    *(float4*)mua = *(const float4*)&st[lane * 4];
    *(float4*)mub = *(const float4*)&st[lane * 4 + 256];
    *(float4*)na  = *(const float4*)&st[512 + lane * 4];
    *(float4*)nb  = *(const float4*)&st[512 + lane * 4 + 256];
    *(float4*)ha  = *(const float4*)&st[1024 + lane * 4];
    *(float4*)hb  = *(const float4*)&st[1024 + lane * 4 + 256];
    const float aca = st[1536 + cl], acb = st[1536 + cl + 16];
    __syncthreads();

    const float* Wt  = W + (size_t)(i0 + wave * 36) * 512 + (lane << 2);
    float* apw       = ap_buf + apbase + (size_t)(i0 + wave * 36) * 32 + cl;
    float* dnx       = denom_next + bb * 288 + i0 + wave * 36;

#pragma unroll
    for (int t = 0; t < 36; ++t) {
        const int il = wave * 36 + t;
        const float4 wva = *(const float4*)(Wt + (size_t)t * 512);
        const float4 wvb = *(const float4*)(Wt + (size_t)t * 512 + 256);
        float pea = 0.f, peb = 0.f;
#pragma unroll
        for (int hc = 0; hc < 4; ++hc) {
            const float4 pv = *(const float4*)&Pt_lds[il * 16 + hc * 4];
            float Va = wva.x * pv.x + wva.y * pv.y + wva.z * pv.z + wva.w * pv.w;
            float Vb = wvb.x * pv.x + wvb.y * pv.y + wvb.z * pv.z + wvb.w * pv.w;
            float da = Va - mua[hc];
            float db = Vb - mub[hc];
            pea += fexp2(fmaf(da * da, na[hc], ha[hc]));
            peb += fexp2(fmaf(db * db, nb[hc], hb[hc]));
        }
        pea += __shfl_xor(pea, 1);
        pea += __shfl_xor(pea, 2);
        peb += __shfl_xor(peb, 1);
        peb += __shfl_xor(peb, 2);
        const float apa = aca * pea;
        const float apb = acb * peb;
        if (hr == 0) {
            apw[(size_t)t * 32]      = apa;
            apw[(size_t)t * 32 + 16] = apb;
        }
        float dsum = apa + apb;
        dsum += __shfl_xor(dsum, 4);
        dsum += __shfl_xor(dsum, 8);
        dsum += __shfl_xor(dsum, 16);
        dsum += __shfl_xor(dsum, 32);
        if (lane == 0)
            atomicAdd(&dnx[t], dsum);
    }
}

extern "C" void kernel_launch(void* const* d_in, const int* in_sizes, int n_in,
                              void* d_out, int out_size, void* d_ws, size_t ws_size,
                              hipStream_t stream)
{
    const float* lambda_p = (const float*)d_in[0];
    const float* poses    = (const float*)d_in[1];
    const float* acts     = (const float*)d_in[2];
    const float* W        = (const float*)d_in[3];
    const float* beta_v   = (const float*)d_in[4];
    const float* beta_a   = (const float*)d_in[5];
    float* out = (float*)d_out;

    float* ws     = (float*)d_ws;
    float* Ptg    = ws;                     // 576*4608 = 2,654,208 floats
    float* actp   = Ptg + 2654208;          // 576*288  =   165,888
    float* ap_buf = actp + 165888;          // 576*9216 = 5,308,416
    float* Mpart  = ap_buf + 5308416;       // 2304*1152 = 2,654,208 (stats alias)
    float* denom0 = Mpart + 2654208;        // 4608
    float* denom1 = denom0 + 4608;          // 4608

    hipMemsetAsync(denom0, 0, 2 * 4608 * sizeof(float), stream);
    m_pass<0><<<2304, 128, 0, stream>>>(poses, acts, Ptg, actp, W, ap_buf, denom1, Mpart);
    f_pass<0><<<576, 64, 0, stream>>>(Mpart, beta_v, beta_a, lambda_p, out);
    e_pass<<<2304, 128, 0, stream>>>(Ptg, Mpart, W, ap_buf, denom0);
    m_pass<1><<<2304, 128, 0, stream>>>(poses, acts, Ptg, actp, W, ap_buf, denom0, Mpart);
    f_pass<0><<<576, 64, 0, stream>>>(Mpart, beta_v, beta_a, lambda_p, out);
    e_pass<<<2304, 128, 0, stream>>>(Ptg, Mpart, W, ap_buf, denom1);
    m_pass<2><<<2304, 128, 0, stream>>>(poses, acts, Ptg, actp, W, ap_buf, denom1, Mpart);
    f_pass<1><<<576, 64, 0, stream>>>(Mpart, beta_v, beta_a, lambda_p, out);
}

// Round 8
// 192.949 us; speedup vs baseline: 9.9321x; 9.1157x over previous
//
#include <hip/hip_runtime.h>

#define EPS 1e-10f
#define HALF_LN2PI 0.91893853320467274f
#define LOG2E 1.4426950408889634f

// b=16, win=14, w=6, ww=36, B_T=32, K=3, Bkk=288 (=i), C_T=32, HH=16
// W flat: [i=288][c=32][hr=4][m=4]
// Pt per (bb,p): [i=288][hc=4][m=4] = patchflat[base(p)+m*4+hc], base(p)=(p/6)*96+(p%6)*16
//
// Grid (m/e): 2304 blocks = (blk = bb*36+p)*4 + iq, 128 threads (2 waves).
// Wave handles 36 i: i = iq*72 + wave*36 + t. 9 blocks/CU, 18 waves/CU (all resident;
// requires VGPR <= 64 tier -> m_pass must stay at moderate unroll, NO full unroll:
// round-7 post-mortem: full unroll of the t-loop spilled acc[18] to scratch ->
// 1.18 GB writes/dispatch, 9x regression. Keep #pragma unroll 6 + plain
// __launch_bounds__(128) here).
// lane = cl*4+hr; thread covers c in {cl, cl+16}, 4 hc each.
// Mpart[bid][k*64+lane], k: [0..3]=S1a [4..7]=S2a [8..11]=S1b [12..15]=S2b [16]=sRa [17]=sRb
// f_pass reduces Mpart over the 4 iq partials and writes stats IN PLACE at
// Mpart[blk*4608 + {0:mu, 512:n2*log2e, 1024:hl*log2e, 1536:a}].
// NOTE (round 6): grid.sync() cooperative fusion = device-scope L2 flush per
// sync -> 770 MB HBM traffic, 6% VALU. Dispatch boundaries are the cheap
// coherence mechanism on MI355X; keep the multi-kernel structure.

__device__ __forceinline__ float fexp2(float x) {
    float r;
    asm("v_exp_f32 %0, %1" : "=v"(r) : "v"(x));
    return r;
}

template <int IT>
__global__ __launch_bounds__(128)
void m_pass(const float* __restrict__ poses, const float* __restrict__ acts,
            float* __restrict__ Ptg, float* __restrict__ actp,
            const float* __restrict__ W,
            const float* __restrict__ ap_buf, const float* __restrict__ denom_prev,
            float* __restrict__ Mpart)
{
    __shared__ __align__(16) float Pt_lds[1152];   // 72 i x 16
    __shared__ float act_lds[72];
    __shared__ float invd_lds[72];
    __shared__ __align__(16) float red[1152];

    const int tid  = threadIdx.x;
    const int wave = tid >> 6, lane = tid & 63;
    const int cl   = lane >> 2;
    const int bid  = blockIdx.x;
    const int blk  = bid >> 2, iq = bid & 3;
    const int bb   = blk / 36, p = blk - bb * 36;
    const int i0   = iq * 72;
    const size_t pbase  = (size_t)blk * 4608;
    const size_t apbase = (size_t)blk * 9216;

    if (IT == 0) {
        const int base = (p / 6) * 96 + (p % 6) * 16;
        for (int e = tid; e < 1152; e += 128) {
            int il = e >> 4, j = e & 15;
            int i = i0 + il;
            int hc = j >> 2, m = j & 3;
            int f = base + m * 4 + hc;              // flat (h,s)
            int h = f / 36, sp = f - h * 36;
            int y = sp / 6, x = sp - y * 6;
            int B = i / 9, kk = i - B * 9;
            int ki = kk / 3, kj = kk - ki * 3;
            float v = poses[(size_t)((bb * 512 + h * 32 + B) * 14 + 2 * x + ki) * 14 + 2 * y + kj];
            Pt_lds[e] = v;
            Ptg[pbase + (size_t)i0 * 16 + e] = v;
        }
        const int y = p / 6, x = p - y * 6;
        for (int e = tid; e < 72; e += 128) {
            int i = i0 + e;
            int B = i / 9, kk = i - B * 9;
            int ki = kk / 3, kj = kk - ki * 3;
            float v = acts[(size_t)((bb * 32 + B) * 14 + 2 * x + ki) * 14 + 2 * y + kj];
            act_lds[e] = v;
            actp[blk * 288 + i] = v;
        }
    } else {
        const float4* src = (const float4*)(Ptg + pbase + (size_t)i0 * 16);
        float4* dst = (float4*)Pt_lds;
        for (int e = tid; e < 288; e += 128) dst[e] = src[e];
        for (int e = tid; e < 72; e += 128) {
            act_lds[e]  = actp[blk * 288 + i0 + e];
            invd_lds[e] = 1.0f / (denom_prev[bb * 288 + i0 + e] + EPS);
        }
    }
    __syncthreads();

    float acc[18];
#pragma unroll
    for (int k = 0; k < 18; ++k) acc[k] = 0.f;

    const float* Wt  = W + (size_t)(i0 + wave * 36) * 512 + (lane << 2);
    const float* apc = ap_buf + apbase + (size_t)(i0 + wave * 36) * 32 + cl;

#pragma unroll 6
    for (int t = 0; t < 36; ++t) {
        const int il = wave * 36 + t;
        const float4 wva = *(const float4*)(Wt + (size_t)t * 512);
        const float4 wvb = *(const float4*)(Wt + (size_t)t * 512 + 256);
        float Ra, Rb;
        if (IT == 0) {
            Ra = 1.0f / 32.0f; Rb = 1.0f / 32.0f;
        } else {
            const float inv = invd_lds[il];
            Ra = fmaf(apc[(size_t)t * 32],      inv, EPS);
            Rb = fmaf(apc[(size_t)t * 32 + 16], inv, EPS);
        }
        const float a_in = act_lds[il];
        const float R4a = Ra * a_in, R4b = Rb * a_in;
        acc[16] += R4a; acc[17] += R4b;
#pragma unroll
        for (int hc = 0; hc < 4; ++hc) {
            const float4 pv = *(const float4*)&Pt_lds[il * 16 + hc * 4];
            float Va = wva.x * pv.x + wva.y * pv.y + wva.z * pv.z + wva.w * pv.w;
            float Vb = wvb.x * pv.x + wvb.y * pv.y + wvb.z * pv.z + wvb.w * pv.w;
            acc[hc]      = fmaf(R4a, Va, acc[hc]);
            acc[4 + hc]  = fmaf(R4a * Va, Va, acc[4 + hc]);
            acc[8 + hc]  = fmaf(R4b, Vb, acc[8 + hc]);
            acc[12 + hc] = fmaf(R4b * Vb, Vb, acc[12 + hc]);
        }
    }

    if (wave == 1) {
#pragma unroll
        for (int k = 0; k < 18; ++k) red[lane * 18 + k] = acc[k];
    }
    __syncthreads();
    if (wave == 0) {
        float* mp = Mpart + (size_t)bid * 1152;
#pragma unroll
        for (int k = 0; k < 18; ++k)
            mp[k * 64 + lane] = acc[k] + red[lane * 18 + k];
    }
}

template <int FINAL>
__global__ __launch_bounds__(64)
void f_pass(float* __restrict__ Mpart, const float* __restrict__ beta_v,
            const float* __restrict__ beta_a, const float* __restrict__ lambda_p,
            float* __restrict__ d_out)
{
    const int lane = threadIdx.x;
    const int cl = lane >> 2, hr = lane & 3;
    const int blk = blockIdx.x;
    const int bb = blk / 36, p = blk - bb * 36;
    float* mp = Mpart + (size_t)blk * 4608;

    float s[18];
#pragma unroll
    for (int k = 0; k < 18; ++k)
        s[k] = mp[k * 64 + lane] + mp[1152 + k * 64 + lane]
             + mp[2304 + k * 64 + lane] + mp[3456 + k * 64 + lane];

    const float lam = lambda_p[0];
    float muv[8], n2v[8], hlv[8], av[2];
#pragma unroll
    for (int q = 0; q < 2; ++q) {
        const int c = cl + q * 16;
        const float sR = s[16 + q];
        float ls = 0.f;
#pragma unroll
        for (int hc = 0; hc < 4; ++hc) {
            const float S1 = s[q * 8 + hc];
            const float S2 = s[q * 8 + 4 + hc];
            const float mu = S1 / sR;
            float ss = S2 / sR - mu * mu;
            ss = fmaxf(ss, 1e-30f);
            muv[q * 4 + hc] = mu;
            // pre-scaled by log2e so e_pass uses a single v_exp_f32 (2^x)
            n2v[q * 4 + hc] = (-0.5f / ss) * LOG2E;
            hlv[q * 4 + hc] = (-0.5f * __logf(ss) - HALF_LN2PI) * LOG2E;
            ls += __logf(sqrtf(ss) + EPS);
        }
        ls += __shfl_xor(ls, 1);
        ls += __shfl_xor(ls, 2);
        const float cost = sR * (16.0f * beta_v[c] + ls);
        av[q] = 1.0f / (1.0f + __expf(-lam * (beta_a[c] - cost)));
    }

    if (FINAL) {
#pragma unroll
        for (int q = 0; q < 2; ++q) {
            const int c = cl + q * 16;
#pragma unroll
            for (int hc = 0; hc < 4; ++hc)
                d_out[(size_t)bb * 18432 + (size_t)(c * 36 + p) * 16 + hr * 4 + hc] = muv[q * 4 + hc];
            if (hr == 0)
                d_out[294912 + (size_t)bb * 1152 + c * 36 + p] = av[q];
        }
    } else {
        // stats written IN PLACE over Mpart[blk]; fence so no store passes an
        // in-flight sibling-lane load of the same region.
        asm volatile("s_waitcnt vmcnt(0)" ::: "memory");
#pragma unroll
        for (int q = 0; q < 2; ++q) {
#pragma unroll
            for (int hc = 0; hc < 4; ++hc) {
                const int ix = lane * 4 + q * 256 + hc;
                mp[ix]        = muv[q * 4 + hc];
                mp[512 + ix]  = n2v[q * 4 + hc];
                mp[1024 + ix] = hlv[q * 4 + hc];
            }
            if (hr == 0) mp[1536 + cl + q * 16] = av[q];
        }
    }
}

__global__ __launch_bounds__(128, 5)
void e_pass(const float* __restrict__ Ptg, const float* __restrict__ Mpart,
            const float* __restrict__ W,
            float* __restrict__ ap_buf, float* __restrict__ denom_next)
{
    __shared__ __align__(16) float Pt_lds[1152];

    const int tid  = threadIdx.x;
    const int wave = tid >> 6, lane = tid & 63;
    const int cl   = lane >> 2, hr = lane & 3;
    const int bid  = blockIdx.x;
    const int blk  = bid >> 2, iq = bid & 3;
    const int bb   = blk / 36;
    const int i0   = iq * 72;
    const size_t pbase  = (size_t)blk * 4608;
    const size_t apbase = (size_t)blk * 9216;

    {
        const float4* src = (const float4*)(Ptg + pbase + (size_t)i0 * 16);
        float4* dst = (float4*)Pt_lds;
        for (int e = tid; e < 288; e += 128) dst[e] = src[e];
    }

    // stats straight to registers (written by f_pass into Mpart[blk])
    const float* st = Mpart + (size_t)blk * 4608;
    __align__(16) float mua[4], mub[4], na[4], nb[4], ha[4], hb[4];
    *(float4*)mua = *(const float4*)&st[lane * 4];
    *(float4*)mub = *(const float4*)&st[lane * 4 + 256];
    *(float4*)na  = *(const float4*)&st[512 + lane * 4];
    *(float4*)nb  = *(const float4*)&st[512 + lane * 4 + 256];
    *(float4*)ha  = *(const float4*)&st[1024 + lane * 4];
    *(float4*)hb  = *(const float4*)&st[1024 + lane * 4 + 256];
    const float aca = st[1536 + cl], acb = st[1536 + cl + 16];
    __syncthreads();

    const float* Wt  = W + (size_t)(i0 + wave * 36) * 512 + (lane << 2);
    float* apw       = ap_buf + apbase + (size_t)(i0 + wave * 36) * 32 + cl;
    float* dnx       = denom_next + bb * 288 + i0 + wave * 36;

#pragma unroll
    for (int t = 0; t < 36; ++t) {
        const int il = wave * 36 + t;
        const float4 wva = *(const float4*)(Wt + (size_t)t * 512);
        const float4 wvb = *(const float4*)(Wt + (size_t)t * 512 + 256);
        float pea = 0.f, peb = 0.f;
#pragma unroll
        for (int hc = 0; hc < 4; ++hc) {
            const float4 pv = *(const float4*)&Pt_lds[il * 16 + hc * 4];
            float Va = wva.x * pv.x + wva.y * pv.y + wva.z * pv.z + wva.w * pv.w;
            float Vb = wvb.x * pv.x + wvb.y * pv.y + wvb.z * pv.z + wvb.w * pv.w;
            float da = Va - mua[hc];
            float db = Vb - mub[hc];
            pea += fexp2(fmaf(da * da, na[hc], ha[hc]));
            peb += fexp2(fmaf(db * db, nb[hc], hb[hc]));
        }
        pea += __shfl_xor(pea, 1);
        pea += __shfl_xor(pea, 2);
        peb += __shfl_xor(peb, 1);
        peb += __shfl_xor(peb, 2);
        const float apa = aca * pea;
        const float apb = acb * peb;
        if (hr == 0) {
            apw[(size_t)t * 32]      = apa;
            apw[(size_t)t * 32 + 16] = apb;
        }
        float dsum = apa + apb;
        dsum += __shfl_xor(dsum, 4);
        dsum += __shfl_xor(dsum, 8);
        dsum += __shfl_xor(dsum, 16);
        dsum += __shfl_xor(dsum, 32);
        if (lane == 0)
            atomicAdd(&dnx[t], dsum);
    }
}

extern "C" void kernel_launch(void* const* d_in, const int* in_sizes, int n_in,
                              void* d_out, int out_size, void* d_ws, size_t ws_size,
                              hipStream_t stream)
{
    const float* lambda_p = (const float*)d_in[0];
    const float* poses    = (const float*)d_in[1];
    const float* acts     = (const float*)d_in[2];
    const float* W        = (const float*)d_in[3];
    const float* beta_v   = (const float*)d_in[4];
    const float* beta_a   = (const float*)d_in[5];
    float* out = (float*)d_out;

    float* ws     = (float*)d_ws;
    float* Ptg    = ws;                     // 576*4608 = 2,654,208 floats
    float* actp   = Ptg + 2654208;          // 576*288  =   165,888
    float* ap_buf = actp + 165888;          // 576*9216 = 5,308,416
    float* Mpart  = ap_buf + 5308416;       // 2304*1152 = 2,654,208 (stats alias)
    float* denom0 = Mpart + 2654208;        // 4608
    float* denom1 = denom0 + 4608;          // 4608

    hipMemsetAsync(denom0, 0, 2 * 4608 * sizeof(float), stream);
    m_pass<0><<<2304, 128, 0, stream>>>(poses, acts, Ptg, actp, W, ap_buf, denom1, Mpart);
    f_pass<0><<<576, 64, 0, stream>>>(Mpart, beta_v, beta_a, lambda_p, out);
    e_pass<<<2304, 128, 0, stream>>>(Ptg, Mpart, W, ap_buf, denom0);
    m_pass<1><<<2304, 128, 0, stream>>>(poses, acts, Ptg, actp, W, ap_buf, denom0, Mpart);
    f_pass<0><<<576, 64, 0, stream>>>(Mpart, beta_v, beta_a, lambda_p, out);
    e_pass<<<2304, 128, 0, stream>>>(Ptg, Mpart, W, ap_buf, denom1);
    m_pass<2><<<2304, 128, 0, stream>>>(poses, acts, Ptg, actp, W, ap_buf, denom1, Mpart);
    f_pass<1><<<576, 64, 0, stream>>>(Mpart, beta_v, beta_a, lambda_p, out);
}

// Round 9
// 184.231 us; speedup vs baseline: 10.4021x; 1.0473x over previous
//
#include <hip/hip_runtime.h>

#define EPS 1e-10f
#define HALF_LN2PI 0.91893853320467274f
#define LOG2E 1.4426950408889634f

// b=16, win=14, w=6, ww=36, B_T=32, K=3, Bkk=288 (=i), C_T=32, HH=16
// W flat: [i=288][c=32][hr=4][m=4]
// Pt per (bb,p): [i=288][hc=4][m=4] = patchflat[base(p)+m*4+hc], base(p)=(p/6)*96+(p%6)*16
//
// Grid (m/e): 2304 blocks = (blk = bb*36+p)*4 + iq, 128 threads (2 waves).
// Wave handles 36 i: i = iq*72 + wave*36 + t. 9 blocks/CU, 18 waves/CU (all resident).
// lane = cl*4+hr; thread covers c in {cl, cl+16}, 4 hc each.
// Mpart[bid][k*64+lane], k: [0..3]=S1a [4..7]=S2a [8..11]=S1b [12..15]=S2b [16]=sRa [17]=sRb
// f_pass reduces Mpart over the 4 iq partials and writes stats IN PLACE at
// Mpart[blk*4608 + {0:mu, 512:n2*log2e, 1024:hl*log2e, 1536:a}].
//
// Post-mortems encoded here:
//  r6: grid.sync() cooperative fusion = device-scope L2 flush per sync (770 MB
//      HBM, 6% VALU). Dispatch boundaries are the cheap coherence mechanism.
//  r7: full unroll of the 36-t loop in m_pass spilled acc[18] -> 1.18 GB
//      scratch writes, 9x regression. m_pass stays at unroll 6, plain bounds.
//  r8: e_pass 5x its VALU floor while structurally-identical m_pass hit 8 us;
//      only difference = in-loop global stores + atomicAdd sharing the vmcnt
//      FIFO with W loads. This version: NO global VMEM ops inside the t-loop —
//      ap goes to LDS, epilogue does coalesced bulk store + 1 atomic per i.

__device__ __forceinline__ float fexp2(float x) {
    float r;
    asm("v_exp_f32 %0, %1" : "=v"(r) : "v"(x));
    return r;
}

template <int IT>
__global__ __launch_bounds__(128)
void m_pass(const float* __restrict__ poses, const float* __restrict__ acts,
            float* __restrict__ Ptg, float* __restrict__ actp,
            const float* __restrict__ W,
            const float* __restrict__ ap_buf, const float* __restrict__ denom_prev,
            float* __restrict__ Mpart)
{
    __shared__ __align__(16) float Pt_lds[1152];   // 72 i x 16
    __shared__ float act_lds[72];
    __shared__ float invd_lds[72];
    __shared__ __align__(16) float red[1152];

    const int tid  = threadIdx.x;
    const int wave = tid >> 6, lane = tid & 63;
    const int cl   = lane >> 2;
    const int bid  = blockIdx.x;
    const int blk  = bid >> 2, iq = bid & 3;
    const int bb   = blk / 36, p = blk - bb * 36;
    const int i0   = iq * 72;
    const size_t pbase  = (size_t)blk * 4608;
    const size_t apbase = (size_t)blk * 9216;

    if (IT == 0) {
        const int base = (p / 6) * 96 + (p % 6) * 16;
        for (int e = tid; e < 1152; e += 128) {
            int il = e >> 4, j = e & 15;
            int i = i0 + il;
            int hc = j >> 2, m = j & 3;
            int f = base + m * 4 + hc;              // flat (h,s)
            int h = f / 36, sp = f - h * 36;
            int y = sp / 6, x = sp - y * 6;
            int B = i / 9, kk = i - B * 9;
            int ki = kk / 3, kj = kk - ki * 3;
            float v = poses[(size_t)((bb * 512 + h * 32 + B) * 14 + 2 * x + ki) * 14 + 2 * y + kj];
            Pt_lds[e] = v;
            Ptg[pbase + (size_t)i0 * 16 + e] = v;
        }
        const int y = p / 6, x = p - y * 6;
        for (int e = tid; e < 72; e += 128) {
            int i = i0 + e;
            int B = i / 9, kk = i - B * 9;
            int ki = kk / 3, kj = kk - ki * 3;
            float v = acts[(size_t)((bb * 32 + B) * 14 + 2 * x + ki) * 14 + 2 * y + kj];
            act_lds[e] = v;
            actp[blk * 288 + i] = v;
        }
    } else {
        const float4* src = (const float4*)(Ptg + pbase + (size_t)i0 * 16);
        float4* dst = (float4*)Pt_lds;
        for (int e = tid; e < 288; e += 128) dst[e] = src[e];
        for (int e = tid; e < 72; e += 128) {
            act_lds[e]  = actp[blk * 288 + i0 + e];
            invd_lds[e] = 1.0f / (denom_prev[bb * 288 + i0 + e] + EPS);
        }
    }
    __syncthreads();

    float acc[18];
#pragma unroll
    for (int k = 0; k < 18; ++k) acc[k] = 0.f;

    const float* Wt  = W + (size_t)(i0 + wave * 36) * 512 + (lane << 2);
    const float* apc = ap_buf + apbase + (size_t)(i0 + wave * 36) * 32 + cl;

#pragma unroll 6
    for (int t = 0; t < 36; ++t) {
        const int il = wave * 36 + t;
        const float4 wva = *(const float4*)(Wt + (size_t)t * 512);
        const float4 wvb = *(const float4*)(Wt + (size_t)t * 512 + 256);
        float Ra, Rb;
        if (IT == 0) {
            Ra = 1.0f / 32.0f; Rb = 1.0f / 32.0f;
        } else {
            const float inv = invd_lds[il];
            Ra = fmaf(apc[(size_t)t * 32],      inv, EPS);
            Rb = fmaf(apc[(size_t)t * 32 + 16], inv, EPS);
        }
        const float a_in = act_lds[il];
        const float R4a = Ra * a_in, R4b = Rb * a_in;
        acc[16] += R4a; acc[17] += R4b;
#pragma unroll
        for (int hc = 0; hc < 4; ++hc) {
            const float4 pv = *(const float4*)&Pt_lds[il * 16 + hc * 4];
            float Va = wva.x * pv.x + wva.y * pv.y + wva.z * pv.z + wva.w * pv.w;
            float Vb = wvb.x * pv.x + wvb.y * pv.y + wvb.z * pv.z + wvb.w * pv.w;
            acc[hc]      = fmaf(R4a, Va, acc[hc]);
            acc[4 + hc]  = fmaf(R4a * Va, Va, acc[4 + hc]);
            acc[8 + hc]  = fmaf(R4b, Vb, acc[8 + hc]);
            acc[12 + hc] = fmaf(R4b * Vb, Vb, acc[12 + hc]);
        }
    }

    if (wave == 1) {
#pragma unroll
        for (int k = 0; k < 18; ++k) red[lane * 18 + k] = acc[k];
    }
    __syncthreads();
    if (wave == 0) {
        float* mp = Mpart + (size_t)bid * 1152;
#pragma unroll
        for (int k = 0; k < 18; ++k)
            mp[k * 64 + lane] = acc[k] + red[lane * 18 + k];
    }
}

template <int FINAL>
__global__ __launch_bounds__(64)
void f_pass(float* __restrict__ Mpart, const float* __restrict__ beta_v,
            const float* __restrict__ beta_a, const float* __restrict__ lambda_p,
            float* __restrict__ d_out)
{
    const int lane = threadIdx.x;
    const int cl = lane >> 2, hr = lane & 3;
    const int blk = blockIdx.x;
    const int bb = blk / 36, p = blk - bb * 36;
    float* mp = Mpart + (size_t)blk * 4608;

    float s[18];
#pragma unroll
    for (int k = 0; k < 18; ++k)
        s[k] = mp[k * 64 + lane] + mp[1152 + k * 64 + lane]
             + mp[2304 + k * 64 + lane] + mp[3456 + k * 64 + lane];

    const float lam = lambda_p[0];
    float muv[8], n2v[8], hlv[8], av[2];
#pragma unroll
    for (int q = 0; q < 2; ++q) {
        const int c = cl + q * 16;
        const float sR = s[16 + q];
        float ls = 0.f;
#pragma unroll
        for (int hc = 0; hc < 4; ++hc) {
            const float S1 = s[q * 8 + hc];
            const float S2 = s[q * 8 + 4 + hc];
            const float mu = S1 / sR;
            float ss = S2 / sR - mu * mu;
            ss = fmaxf(ss, 1e-30f);
            muv[q * 4 + hc] = mu;
            // pre-scaled by log2e so e_pass uses a single v_exp_f32 (2^x)
            n2v[q * 4 + hc] = (-0.5f / ss) * LOG2E;
            hlv[q * 4 + hc] = (-0.5f * __logf(ss) - HALF_LN2PI) * LOG2E;
            ls += __logf(sqrtf(ss) + EPS);
        }
        ls += __shfl_xor(ls, 1);
        ls += __shfl_xor(ls, 2);
        const float cost = sR * (16.0f * beta_v[c] + ls);
        av[q] = 1.0f / (1.0f + __expf(-lam * (beta_a[c] - cost)));
    }

    if (FINAL) {
#pragma unroll
        for (int q = 0; q < 2; ++q) {
            const int c = cl + q * 16;
#pragma unroll
            for (int hc = 0; hc < 4; ++hc)
                d_out[(size_t)bb * 18432 + (size_t)(c * 36 + p) * 16 + hr * 4 + hc] = muv[q * 4 + hc];
            if (hr == 0)
                d_out[294912 + (size_t)bb * 1152 + c * 36 + p] = av[q];
        }
    } else {
        // stats written IN PLACE over Mpart[blk]; fence so no store passes an
        // in-flight sibling-lane load of the same region.
        asm volatile("s_waitcnt vmcnt(0)" ::: "memory");
#pragma unroll
        for (int q = 0; q < 2; ++q) {
#pragma unroll
            for (int hc = 0; hc < 4; ++hc) {
                const int ix = lane * 4 + q * 256 + hc;
                mp[ix]        = muv[q * 4 + hc];
                mp[512 + ix]  = n2v[q * 4 + hc];
                mp[1024 + ix] = hlv[q * 4 + hc];
            }
            if (hr == 0) mp[1536 + cl + q * 16] = av[q];
        }
    }
}

__global__ __launch_bounds__(128)
void e_pass(const float* __restrict__ Ptg, const float* __restrict__ Mpart,
            const float* __restrict__ W,
            float* __restrict__ ap_buf, float* __restrict__ denom_next)
{
    __shared__ __align__(16) float Pt_lds[1152];
    __shared__ __align__(16) float ap_lds[2304];   // 72 i x 32 c

    const int tid  = threadIdx.x;
    const int wave = tid >> 6, lane = tid & 63;
    const int cl   = lane >> 2, hr = lane & 3;
    const int bid  = blockIdx.x;
    const int blk  = bid >> 2, iq = bid & 3;
    const int bb   = blk / 36;
    const int i0   = iq * 72;
    const size_t pbase  = (size_t)blk * 4608;
    const size_t apbase = (size_t)blk * 9216;

    {
        const float4* src = (const float4*)(Ptg + pbase + (size_t)i0 * 16);
        float4* dst = (float4*)Pt_lds;
        for (int e = tid; e < 288; e += 128) dst[e] = src[e];
    }

    // stats straight to registers (written by f_pass into Mpart[blk])
    const float* st = Mpart + (size_t)blk * 4608;
    __align__(16) float mua[4], mub[4], na[4], nb[4], ha[4], hb[4];
    *(float4*)mua = *(const float4*)&st[lane * 4];
    *(float4*)mub = *(const float4*)&st[lane * 4 + 256];
    *(float4*)na  = *(const float4*)&st[512 + lane * 4];
    *(float4*)nb  = *(const float4*)&st[512 + lane * 4 + 256];
    *(float4*)ha  = *(const float4*)&st[1024 + lane * 4];
    *(float4*)hb  = *(const float4*)&st[1024 + lane * 4 + 256];
    const float aca = st[1536 + cl], acb = st[1536 + cl + 16];
    __syncthreads();

    const float* Wt = W + (size_t)(i0 + wave * 36) * 512 + (lane << 2);

    // ---- t-loop: NO global stores/atomics inside (r8 post-mortem) ----
#pragma unroll 6
    for (int t = 0; t < 36; ++t) {
        const int il = wave * 36 + t;
        const float4 wva = *(const float4*)(Wt + (size_t)t * 512);
        const float4 wvb = *(const float4*)(Wt + (size_t)t * 512 + 256);
        float pea = 0.f, peb = 0.f;
#pragma unroll
        for (int hc = 0; hc < 4; ++hc) {
            const float4 pv = *(const float4*)&Pt_lds[il * 16 + hc * 4];
            float Va = wva.x * pv.x + wva.y * pv.y + wva.z * pv.z + wva.w * pv.w;
            float Vb = wvb.x * pv.x + wvb.y * pv.y + wvb.z * pv.z + wvb.w * pv.w;
            float da = Va - mua[hc];
            float db = Vb - mub[hc];
            pea += fexp2(fmaf(da * da, na[hc], ha[hc]));
            peb += fexp2(fmaf(db * db, nb[hc], hb[hc]));
        }
        pea += __shfl_xor(pea, 1);
        pea += __shfl_xor(pea, 2);
        peb += __shfl_xor(peb, 1);
        peb += __shfl_xor(peb, 2);
        if (hr == 0) {
            ap_lds[il * 32 + cl]      = aca * pea;   // banks cl / cl+16: conflict-free
            ap_lds[il * 32 + cl + 16] = acb * peb;
        }
    }
    __syncthreads();

    // ---- epilogue: coalesced bulk store of ap + one atomic per i ----
    {
        const float4* s4 = (const float4*)ap_lds;
        float4* d4 = (float4*)(ap_buf + apbase + (size_t)i0 * 32);
        for (int e = tid; e < 576; e += 128) d4[e] = s4[e];
    }
    if (tid < 72) {
        float s = 0.f;
#pragma unroll
        for (int c = 0; c < 32; ++c)
            s += ap_lds[tid * 32 + ((c + tid) & 31)];   // bank-rotated: no conflicts
        atomicAdd(&denom_next[bb * 288 + i0 + tid], s);
    }
}

extern "C" void kernel_launch(void* const* d_in, const int* in_sizes, int n_in,
                              void* d_out, int out_size, void* d_ws, size_t ws_size,
                              hipStream_t stream)
{
    const float* lambda_p = (const float*)d_in[0];
    const float* poses    = (const float*)d_in[1];
    const float* acts     = (const float*)d_in[2];
    const float* W        = (const float*)d_in[3];
    const float* beta_v   = (const float*)d_in[4];
    const float* beta_a   = (const float*)d_in[5];
    float* out = (float*)d_out;

    float* ws     = (float*)d_ws;
    float* Ptg    = ws;                     // 576*4608 = 2,654,208 floats
    float* actp   = Ptg + 2654208;          // 576*288  =   165,888
    float* ap_buf = actp + 165888;          // 576*9216 = 5,308,416
    float* Mpart  = ap_buf + 5308416;       // 2304*1152 = 2,654,208 (stats alias)
    float* denom0 = Mpart + 2654208;        // 4608
    float* denom1 = denom0 + 4608;          // 4608

    hipMemsetAsync(denom0, 0, 2 * 4608 * sizeof(float), stream);
    m_pass<0><<<2304, 128, 0, stream>>>(poses, acts, Ptg, actp, W, ap_buf, denom1, Mpart);
    f_pass<0><<<576, 64, 0, stream>>>(Mpart, beta_v, beta_a, lambda_p, out);
    e_pass<<<2304, 128, 0, stream>>>(Ptg, Mpart, W, ap_buf, denom0);
    m_pass<1><<<2304, 128, 0, stream>>>(poses, acts, Ptg, actp, W, ap_buf, denom0, Mpart);
    f_pass<0><<<576, 64, 0, stream>>>(Mpart, beta_v, beta_a, lambda_p, out);
    e_pass<<<2304, 128, 0, stream>>>(Ptg, Mpart, W, ap_buf, denom1);
    m_pass<2><<<2304, 128, 0, stream>>>(poses, acts, Ptg, actp, W, ap_buf, denom1, Mpart);
    f_pass<1><<<576, 64, 0, stream>>>(Mpart, beta_v, beta_a, lambda_p, out);
}

// Round 10
// 176.315 us; speedup vs baseline: 10.8691x; 1.0449x over previous
//
#include <hip/hip_runtime.h>

#define EPS 1e-10f
#define HALF_LN2PI 0.91893853320467274f
#define LOG2E 1.4426950408889634f

// b=16, win=14, w=6, ww=36, B_T=32, K=3, Bkk=288 (=i), C_T=32, HH=16
// W flat: [i=288][c=32][hr=4][m=4]
// Pt per (bb,p): [i=288][hc=4][m=4] = patchflat[base(p)+m*4+hc], base(p)=(p/6)*96+(p%6)*16
//
// Grid (m/e): 2304 blocks = (blk = bb*36+p)*4 + iq, 128 threads (2 waves).
// Wave handles 36 i: i = iq*72 + wave*36 + t. 9 blocks/CU, 18 waves/CU (all resident;
// requires VGPR <= 64 tier in m/e kernels).
// lane = cl*4+hr; thread covers c in {cl, cl+16}, 4 hc each.
// Mpart[bid][k*64+lane], k: [0..3]=S1a [4..7]=S2a [8..11]=S1b [12..15]=S2b [16]=sRa [17]=sRb
// f_pass reduces Mpart over the 4 iq partials and writes stats IN PLACE at
// Mpart[blk*4608 + {0:mu, 512:n2*log2e, 1024:hl*log2e, 1536:a}]; it ALSO zeroes
// the denom buffer used by the NEXT e_pass (replaces the 43us fillBuffer dispatch, r9).
//
// Post-mortems encoded here:
//  r6: grid.sync() cooperative fusion = device-scope L2 flush per sync. Dispatch
//      boundaries are the cheap coherence mechanism on MI355X.
//  r7: full unroll of the 36-t loop in m_pass spilled acc[18] -> 1.18 GB scratch
//      writes, 9x regression. m_pass stays at unroll 6, plain bounds.
//  r8: in-loop global stores + atomicAdd share the vmcnt FIFO with W loads ->
//      e_pass 5x its floor. NO global VMEM ops inside t-loops; ap via LDS.
//  r9: hipMemsetAsync = ~43us fillBufferAligned dispatch per call -> zero denoms
//      inside f_pass<0> instead. Quad-reduce via DPP (VALU) not shfl (LDS pipe).

__device__ __forceinline__ float fexp2(float x) {
    float r;
    asm("v_exp_f32 %0, %1" : "=v"(r) : "v"(x));
    return r;
}
// quad-level XOR butterfly adds via DPP (single VALU op each, no LDS pipe)
__device__ __forceinline__ float qxor1_add(float x) {
    float r;
    asm("v_add_f32 %0, %1, %1 quad_perm:[1,0,3,2] row_mask:0xf bank_mask:0xf"
        : "=v"(r) : "v"(x));
    return r;
}
__device__ __forceinline__ float qxor2_add(float x) {
    float r;
    asm("v_add_f32 %0, %1, %1 quad_perm:[2,3,0,1] row_mask:0xf bank_mask:0xf"
        : "=v"(r) : "v"(x));
    return r;
}

template <int IT>
__global__ __launch_bounds__(128)
void m_pass(const float* __restrict__ poses, const float* __restrict__ acts,
            float* __restrict__ Ptg, float* __restrict__ actp,
            const float* __restrict__ W,
            const float* __restrict__ ap_buf, const float* __restrict__ denom_prev,
            float* __restrict__ Mpart)
{
    __shared__ __align__(16) float Pt_lds[1152];   // 72 i x 16
    __shared__ float act_lds[72];
    __shared__ float invd_lds[72];
    __shared__ __align__(16) float red[1152];

    const int tid  = threadIdx.x;
    const int wave = tid >> 6, lane = tid & 63;
    const int cl   = lane >> 2;
    const int bid  = blockIdx.x;
    const int blk  = bid >> 2, iq = bid & 3;
    const int bb   = blk / 36, p = blk - bb * 36;
    const int i0   = iq * 72;
    const size_t pbase  = (size_t)blk * 4608;
    const size_t apbase = (size_t)blk * 9216;

    if (IT == 0) {
        const int base = (p / 6) * 96 + (p % 6) * 16;
        for (int e = tid; e < 1152; e += 128) {
            int il = e >> 4, j = e & 15;
            int i = i0 + il;
            int hc = j >> 2, m = j & 3;
            int f = base + m * 4 + hc;              // flat (h,s)
            int h = f / 36, sp = f - h * 36;
            int y = sp / 6, x = sp - y * 6;
            int B = i / 9, kk = i - B * 9;
            int ki = kk / 3, kj = kk - ki * 3;
            float v = poses[(size_t)((bb * 512 + h * 32 + B) * 14 + 2 * x + ki) * 14 + 2 * y + kj];
            Pt_lds[e] = v;
            Ptg[pbase + (size_t)i0 * 16 + e] = v;
        }
        const int y = p / 6, x = p - y * 6;
        for (int e = tid; e < 72; e += 128) {
            int i = i0 + e;
            int B = i / 9, kk = i - B * 9;
            int ki = kk / 3, kj = kk - ki * 3;
            float v = acts[(size_t)((bb * 32 + B) * 14 + 2 * x + ki) * 14 + 2 * y + kj];
            act_lds[e] = v;
            actp[blk * 288 + i] = v;
        }
    } else {
        const float4* src = (const float4*)(Ptg + pbase + (size_t)i0 * 16);
        float4* dst = (float4*)Pt_lds;
        for (int e = tid; e < 288; e += 128) dst[e] = src[e];
        for (int e = tid; e < 72; e += 128) {
            act_lds[e]  = actp[blk * 288 + i0 + e];
            invd_lds[e] = 1.0f / (denom_prev[bb * 288 + i0 + e] + EPS);
        }
    }
    __syncthreads();

    float acc[18];
#pragma unroll
    for (int k = 0; k < 18; ++k) acc[k] = 0.f;

    const float* Wt  = W + (size_t)(i0 + wave * 36) * 512 + (lane << 2);
    const float* apc = ap_buf + apbase + (size_t)(i0 + wave * 36) * 32 + cl;

#pragma unroll 6
    for (int t = 0; t < 36; ++t) {
        const int il = wave * 36 + t;
        const float4 wva = *(const float4*)(Wt + (size_t)t * 512);
        const float4 wvb = *(const float4*)(Wt + (size_t)t * 512 + 256);
        float Ra, Rb;
        if (IT == 0) {
            Ra = 1.0f / 32.0f; Rb = 1.0f / 32.0f;
        } else {
            const float inv = invd_lds[il];
            Ra = fmaf(apc[(size_t)t * 32],      inv, EPS);
            Rb = fmaf(apc[(size_t)t * 32 + 16], inv, EPS);
        }
        const float a_in = act_lds[il];
        const float R4a = Ra * a_in, R4b = Rb * a_in;
        acc[16] += R4a; acc[17] += R4b;
#pragma unroll
        for (int hc = 0; hc < 4; ++hc) {
            const float4 pv = *(const float4*)&Pt_lds[il * 16 + hc * 4];
            float Va = wva.x * pv.x + wva.y * pv.y + wva.z * pv.z + wva.w * pv.w;
            float Vb = wvb.x * pv.x + wvb.y * pv.y + wvb.z * pv.z + wvb.w * pv.w;
            acc[hc]      = fmaf(R4a, Va, acc[hc]);
            acc[4 + hc]  = fmaf(R4a * Va, Va, acc[4 + hc]);
            acc[8 + hc]  = fmaf(R4b, Vb, acc[8 + hc]);
            acc[12 + hc] = fmaf(R4b * Vb, Vb, acc[12 + hc]);
        }
    }

    if (wave == 1) {
#pragma unroll
        for (int k = 0; k < 18; ++k) red[lane * 18 + k] = acc[k];
    }
    __syncthreads();
    if (wave == 0) {
        float* mp = Mpart + (size_t)bid * 1152;
#pragma unroll
        for (int k = 0; k < 18; ++k)
            mp[k * 64 + lane] = acc[k] + red[lane * 18 + k];
    }
}

template <int FINAL>
__global__ __launch_bounds__(64)
void f_pass(float* __restrict__ Mpart, const float* __restrict__ beta_v,
            const float* __restrict__ beta_a, const float* __restrict__ lambda_p,
            float* __restrict__ d_out, float* __restrict__ denom_zero)
{
    const int lane = threadIdx.x;
    const int cl = lane >> 2, hr = lane & 3;
    const int blk = blockIdx.x;
    const int bb = blk / 36, p = blk - bb * 36;
    float* mp = Mpart + (size_t)blk * 4608;

    // zero the denom buffer the NEXT e_pass accumulates into (replaces the
    // 43us fillBufferAligned dispatch; ordering by dispatch boundary).
    if (!FINAL && lane < 8)
        denom_zero[blk * 8 + lane] = 0.0f;

    float s[18];
#pragma unroll
    for (int k = 0; k < 18; ++k)
        s[k] = mp[k * 64 + lane] + mp[1152 + k * 64 + lane]
             + mp[2304 + k * 64 + lane] + mp[3456 + k * 64 + lane];

    const float lam = lambda_p[0];
    float muv[8], n2v[8], hlv[8], av[2];
#pragma unroll
    for (int q = 0; q < 2; ++q) {
        const int c = cl + q * 16;
        const float sR = s[16 + q];
        float ls = 0.f;
#pragma unroll
        for (int hc = 0; hc < 4; ++hc) {
            const float S1 = s[q * 8 + hc];
            const float S2 = s[q * 8 + 4 + hc];
            const float mu = S1 / sR;
            float ss = S2 / sR - mu * mu;
            ss = fmaxf(ss, 1e-30f);
            muv[q * 4 + hc] = mu;
            // pre-scaled by log2e so e_pass uses a single v_exp_f32 (2^x)
            n2v[q * 4 + hc] = (-0.5f / ss) * LOG2E;
            hlv[q * 4 + hc] = (-0.5f * __logf(ss) - HALF_LN2PI) * LOG2E;
            ls += __logf(sqrtf(ss) + EPS);
        }
        ls += __shfl_xor(ls, 1);
        ls += __shfl_xor(ls, 2);
        const float cost = sR * (16.0f * beta_v[c] + ls);
        av[q] = 1.0f / (1.0f + __expf(-lam * (beta_a[c] - cost)));
    }

    if (FINAL) {
#pragma unroll
        for (int q = 0; q < 2; ++q) {
            const int c = cl + q * 16;
#pragma unroll
            for (int hc = 0; hc < 4; ++hc)
                d_out[(size_t)bb * 18432 + (size_t)(c * 36 + p) * 16 + hr * 4 + hc] = muv[q * 4 + hc];
            if (hr == 0)
                d_out[294912 + (size_t)bb * 1152 + c * 36 + p] = av[q];
        }
    } else {
        // stats written IN PLACE over Mpart[blk]; fence so no store passes an
        // in-flight sibling-lane load of the same region.
        asm volatile("s_waitcnt vmcnt(0)" ::: "memory");
#pragma unroll
        for (int q = 0; q < 2; ++q) {
#pragma unroll
            for (int hc = 0; hc < 4; ++hc) {
                const int ix = lane * 4 + q * 256 + hc;
                mp[ix]        = muv[q * 4 + hc];
                mp[512 + ix]  = n2v[q * 4 + hc];
                mp[1024 + ix] = hlv[q * 4 + hc];
            }
            if (hr == 0) mp[1536 + cl + q * 16] = av[q];
        }
    }
}

__global__ __launch_bounds__(128)
void e_pass(const float* __restrict__ Ptg, const float* __restrict__ Mpart,
            const float* __restrict__ W,
            float* __restrict__ ap_buf, float* __restrict__ denom_next)
{
    __shared__ __align__(16) float Pt_lds[1152];
    __shared__ __align__(16) float ap_lds[2304];   // 72 i x 32 c

    const int tid  = threadIdx.x;
    const int wave = tid >> 6, lane = tid & 63;
    const int cl   = lane >> 2, hr = lane & 3;
    const int bid  = blockIdx.x;
    const int blk  = bid >> 2, iq = bid & 3;
    const int bb   = blk / 36;
    const int i0   = iq * 72;
    const size_t pbase  = (size_t)blk * 4608;
    const size_t apbase = (size_t)blk * 9216;

    {
        const float4* src = (const float4*)(Ptg + pbase + (size_t)i0 * 16);
        float4* dst = (float4*)Pt_lds;
        for (int e = tid; e < 288; e += 128) dst[e] = src[e];
    }

    // stats straight to registers (written by f_pass into Mpart[blk])
    const float* st = Mpart + (size_t)blk * 4608;
    __align__(16) float mua[4], mub[4], na[4], nb[4], ha[4], hb[4];
    *(float4*)mua = *(const float4*)&st[lane * 4];
    *(float4*)mub = *(const float4*)&st[lane * 4 + 256];
    *(float4*)na  = *(const float4*)&st[512 + lane * 4];
    *(float4*)nb  = *(const float4*)&st[512 + lane * 4 + 256];
    *(float4*)ha  = *(const float4*)&st[1024 + lane * 4];
    *(float4*)hb  = *(const float4*)&st[1024 + lane * 4 + 256];
    const float aca = st[1536 + cl], acb = st[1536 + cl + 16];
    __syncthreads();

    const float* Wt = W + (size_t)(i0 + wave * 36) * 512 + (lane << 2);

    // ---- t-loop: NO global VMEM inside (r8); quad-reduce via DPP (r9) ----
#pragma unroll 6
    for (int t = 0; t < 36; ++t) {
        const int il = wave * 36 + t;
        const float4 wva = *(const float4*)(Wt + (size_t)t * 512);
        const float4 wvb = *(const float4*)(Wt + (size_t)t * 512 + 256);
        float pea = 0.f, peb = 0.f;
#pragma unroll
        for (int hc = 0; hc < 4; ++hc) {
            const float4 pv = *(const float4*)&Pt_lds[il * 16 + hc * 4];
            float Va = wva.x * pv.x + wva.y * pv.y + wva.z * pv.z + wva.w * pv.w;
            float Vb = wvb.x * pv.x + wvb.y * pv.y + wvb.z * pv.z + wvb.w * pv.w;
            float da = Va - mua[hc];
            float db = Vb - mub[hc];
            pea += fexp2(fmaf(da * da, na[hc], ha[hc]));
            peb += fexp2(fmaf(db * db, nb[hc], hb[hc]));
        }
        pea = qxor1_add(pea);
        pea = qxor2_add(pea);
        peb = qxor1_add(peb);
        peb = qxor2_add(peb);
        if (hr == 0) {
            ap_lds[il * 32 + cl]      = aca * pea;   // banks cl / cl+16: conflict-free
            ap_lds[il * 32 + cl + 16] = acb * peb;
        }
    }
    __syncthreads();

    // ---- epilogue: coalesced bulk store of ap + one atomic per i ----
    {
        const float4* s4 = (const float4*)ap_lds;
        float4* d4 = (float4*)(ap_buf + apbase + (size_t)i0 * 32);
        for (int e = tid; e < 576; e += 128) d4[e] = s4[e];
    }
    if (tid < 72) {
        float s = 0.f;
#pragma unroll
        for (int c = 0; c < 32; ++c)
            s += ap_lds[tid * 32 + ((c + tid) & 31)];   // bank-rotated: no conflicts
        atomicAdd(&denom_next[bb * 288 + i0 + tid], s);
    }
}

extern "C" void kernel_launch(void* const* d_in, const int* in_sizes, int n_in,
                              void* d_out, int out_size, void* d_ws, size_t ws_size,
                              hipStream_t stream)
{
    const float* lambda_p = (const float*)d_in[0];
    const float* poses    = (const float*)d_in[1];
    const float* acts     = (const float*)d_in[2];
    const float* W        = (const float*)d_in[3];
    const float* beta_v   = (const float*)d_in[4];
    const float* beta_a   = (const float*)d_in[5];
    float* out = (float*)d_out;

    float* ws     = (float*)d_ws;
    float* Ptg    = ws;                     // 576*4608 = 2,654,208 floats
    float* actp   = Ptg + 2654208;          // 576*288  =   165,888
    float* ap_buf = actp + 165888;          // 576*9216 = 5,308,416
    float* Mpart  = ap_buf + 5308416;       // 2304*1152 = 2,654,208 (stats alias)
    float* denom0 = Mpart + 2654208;        // 4608
    float* denom1 = denom0 + 4608;          // 4608

    m_pass<0><<<2304, 128, 0, stream>>>(poses, acts, Ptg, actp, W, ap_buf, denom1, Mpart);
    f_pass<0><<<576, 64, 0, stream>>>(Mpart, beta_v, beta_a, lambda_p, out, denom0);
    e_pass<<<2304, 128, 0, stream>>>(Ptg, Mpart, W, ap_buf, denom0);
    m_pass<1><<<2304, 128, 0, stream>>>(poses, acts, Ptg, actp, W, ap_buf, denom0, Mpart);
    f_pass<0><<<576, 64, 0, stream>>>(Mpart, beta_v, beta_a, lambda_p, out, denom1);
    e_pass<<<2304, 128, 0, stream>>>(Ptg, Mpart, W, ap_buf, denom1);
    m_pass<2><<<2304, 128, 0, stream>>>(poses, acts, Ptg, actp, W, ap_buf, denom1, Mpart);
    f_pass<1><<<576, 64, 0, stream>>>(Mpart, beta_v, beta_a, lambda_p, out, denom0);
}